// Round 10
// baseline (1389.735 us; speedup 1.0000x reference)
//
#include <hip/hip_runtime.h>
#include <hip/hip_bf16.h>
#include <cstdint>
#include <cstddef>

typedef _Float16 half8 __attribute__((ext_vector_type(8)));
typedef _Float16 half4 __attribute__((ext_vector_type(4)));
typedef float floatx4 __attribute__((ext_vector_type(4)));
typedef unsigned long long u64;

#define B_ 256
#define T_ 168
#define H_ 1024
#define WS_ 64
#define LAG_ 168
#define LAT_ 128

__device__ __forceinline__ float fast_sigmoid(float x) {
    return __builtin_amdgcn_rcpf(1.f + __expf(-x));
}
__device__ __forceinline__ float fast_tanh(float x) {
    return 1.f - 2.f * __builtin_amdgcn_rcpf(__expf(2.f * x) + 1.f);
}

// ---------------- fp32 -> fp16 conversion ----------------
__global__ void cvt_f32_f16_v4(const float4* __restrict__ src, half4* __restrict__ dst, int n4) {
    int i = blockIdx.x * blockDim.x + threadIdx.x;
    if (i < n4) {
        float4 v = src[i];
        half4 o;
        o[0] = (_Float16)v.x; o[1] = (_Float16)v.y;
        o[2] = (_Float16)v.z; o[3] = (_Float16)v.w;
        dst[i] = o;
    }
}

// ---------------- encoder layers 1,2 ----------------
__global__ void enc12(const float* __restrict__ in, const float* __restrict__ W,
                      const float* __restrict__ bias, float* __restrict__ outb, int infeat) {
    int r = blockIdx.x, j = threadIdx.x;
    const float* row = in + (size_t)r * infeat;
    const float* w   = W  + (size_t)j * infeat;
    float s = bias[j];
    for (int k = 0; k < infeat; ++k) s += row[k] * w[k];
    outb[(size_t)r * blockDim.x + j] = (s >= 0.f) ? s : 0.01f * s;
}

// ---------------- encoder layer 3 ----------------
__global__ void enc3(const float* __restrict__ h2, const float* __restrict__ W3,
                     const float* __restrict__ b3, float* __restrict__ hprev32,
                     _Float16* __restrict__ h0f16) {
    __shared__ float s[LAT_];
    int r = blockIdx.x;
    if (threadIdx.x < LAT_) s[threadIdx.x] = h2[(size_t)r * LAT_ + threadIdx.x];
    __syncthreads();
    for (int j = threadIdx.x; j < H_; j += 256) {
        const float* w = W3 + (size_t)j * LAT_;
        float acc = b3[j];
        #pragma unroll 8
        for (int k = 0; k < LAT_; ++k) acc += s[k] * w[k];
        hprev32[(size_t)r * H_ + j] = acc;
        h0f16[(size_t)r * H_ + j]   = (_Float16)acc;
    }
}

// ---------------- persistent GRU: phase-pipelined, 2 WGs/CU ----------------
// 512 WGs x 128 thr (2 waves), 2 WGs/CU (LDS 47.9KBx2=95.8<=160; 4 waves/CU,
// 1/SIMD; R5 precedent for co-residency at this shape). pi = ((blk&15)+(blk>>8))&15
// so CU-co-located WGs differ in pi under BOTH sequential and round-robin(+256)
// placement -> their phase-0 stalls anti-correlate -> sibling WG's compute hides
// the publish->flag->poll->stage chain. Per wave identical to R9: 16 units x 3
// gates, rz Whh resident (AGPRs), n streamed 8+8, per-wave flags, 4-phase K-loop
// with cached-ballot polling, __threadfence_block before the u64 publish read.
__global__ __launch_bounds__(128, 1) void gru_persistent(
    _Float16* __restrict__ hbuf,
    const float* __restrict__ hprev32, const _Float16* __restrict__ whh16,
    const _Float16* __restrict__ wih16, const _Float16* __restrict__ x16,
    const float* __restrict__ bih, const float* __restrict__ bhh,
    const float* __restrict__ Wo, float* __restrict__ partials,
    unsigned* __restrict__ bar)
{
    __shared__ __align__(16) _Float16 Ash[16 * 1032];   // 33.0 KB
    __shared__ __align__(16) _Float16 Wsh[96 * 72];     // 13.8 KB
    __shared__ __align__(16) _Float16 Hsh[2 * 256];     // per-wave transpose segs

    const int tid  = threadIdx.x;
    const int w    = tid >> 6;
    const int lane = tid & 63;
    const int m16  = lane & 15;
    const int quad = lane >> 4;
    const int blk  = blockIdx.x;
    const int pi   = ((blk & 15) + (blk >> 8)) & 15;   // co-located WGs: different pi
    const int qi   = (blk >> 4) & 31;
    const int pi16 = pi << 4;
    const int u    = (qi << 5) + (w << 4) + m16;
    const int slice_self = (qi << 1) | w;              // 0..63 within pi-group

    // Wih slice -> LDS (once): 96 rows (3 gates x 32 units) x 64k
    for (int idx = tid; idx < 768; idx += 128) {
        int rowl = idx >> 3, ch = idx & 7;
        int g = rowl >> 5, ru = rowl & 31;
        *(uint4*)(&Wsh[rowl * 72 + (ch << 3)]) =
            *(const uint4*)(wih16 + (size_t)(((g << 10) + (qi << 5) + ru) << 6) + (ch << 3));
    }

    // Resident Whh: r,z gates (AGPR-backed)
    half8 br[32], bz[32];
    {
        const _Float16* p0 = whh16 + ((size_t)u << 10) + (quad << 3);
        const _Float16* p1 = whh16 + ((size_t)(H_ + u) << 10) + (quad << 3);
        #pragma unroll
        for (int c = 0; c < 32; ++c) br[c] = *(const half8*)(p0 + (c << 5));
        #pragma unroll
        for (int c = 0; c < 32; ++c) bz[c] = *(const half8*)(p1 + (c << 5));
    }
    const _Float16* bnp = whh16 + ((size_t)(2 * H_ + u) << 10) + (quad << 3);

    const float b_r  = bih[u]          + bhh[u];
    const float b_z  = bih[H_ + u]     + bhh[H_ + u];
    const float b_in = bih[2 * H_ + u];
    const float b_hn = bhh[2 * H_ + u];
    const float wo_u = Wo[u];

    float hreg[4];
    #pragma unroll
    for (int i = 0; i < 4; ++i)
        hreg[i] = hprev32[((size_t)(pi16 + (quad << 2) + i) << 10) + u];

    __syncthreads();

    // per-wave flag lines: index (pi<<6 | slice), 64B stride
    unsigned* flag_self       = bar + (((pi << 6) | slice_self) << 4);
    const unsigned* flag_peer = bar + (((pi << 6) | lane) << 4);
    const int srow = tid >> 3;     // staging row 0..15
    const int sch  = tid & 7;      // 64B chunk within 512B phase-row
    const int prow = lane >> 2;    // publish row, 8B chunk
    const int pc4  = lane & 3;

    for (int t = 0; t < T_; ++t) {
        const _Float16* hsrc = hbuf + (size_t)(t & 3) * (B_ * H_);
        _Float16*       hdst = hbuf + (size_t)((t + 1) & 3) * (B_ * H_);

        // h-independent prefetch (flies under the poll)
        half8 ax0 = *(const half8*)(x16 + (((size_t)t << 8) + pi16 + m16) * WS_ + (quad << 3));
        half8 ax1 = *(const half8*)(x16 + (((size_t)t << 8) + pi16 + m16) * WS_ + 32 + (quad << 3));
        half8 bnA[8], bnB[8];
        #pragma unroll
        for (int j = 0; j < 8; ++j) bnA[j] = *(const half8*)(bnp + (j << 5));

        const unsigned need = (unsigned)t;
        u64 rdy = 0;

        // wait phase 0 (slices 0..15 = units [0,256))
        while ((rdy & 0xFFFFull) != 0xFFFFull) {
            unsigned f = __hip_atomic_load(flag_peer, __ATOMIC_RELAXED, __HIP_MEMORY_SCOPE_AGENT);
            rdy |= __ballot(f >= need);
            if ((rdy & 0xFFFFull) != 0xFFFFull) __builtin_amdgcn_s_sleep(1);
        }
        // issue phase-0 A loads: 8 u64 = 64B per thread
        u64 va[8];
        {
            const _Float16* s = hsrc + ((size_t)(pi16 + srow) << 10) + (sch << 5);
            #pragma unroll
            for (int j = 0; j < 8; ++j)
                va[j] = __hip_atomic_load((const u64*)(s + (j << 2)), __ATOMIC_RELAXED, __HIP_MEMORY_SCOPE_AGENT);
        }

        floatx4 acc_r  = {b_r,  b_r,  b_r,  b_r };
        floatx4 acc_z  = {b_z,  b_z,  b_z,  b_z };
        floatx4 acc_in = {b_in, b_in, b_in, b_in};
        floatx4 acc_hn = {b_hn, b_hn, b_hn, b_hn};

        // gi = x_t @ Wih^T (fills the phase-0 stage window)
        {
            half8 p0 = *(const half8*)(&Wsh[((w << 4) + m16) * 72       + (quad << 3)]);
            half8 p1 = *(const half8*)(&Wsh[(32 + (w << 4) + m16) * 72  + (quad << 3)]);
            half8 p2 = *(const half8*)(&Wsh[(64 + (w << 4) + m16) * 72  + (quad << 3)]);
            acc_r  = __builtin_amdgcn_mfma_f32_16x16x32_f16(ax0, p0, acc_r,  0, 0, 0);
            acc_z  = __builtin_amdgcn_mfma_f32_16x16x32_f16(ax0, p1, acc_z,  0, 0, 0);
            acc_in = __builtin_amdgcn_mfma_f32_16x16x32_f16(ax0, p2, acc_in, 0, 0, 0);
            half8 q0 = *(const half8*)(&Wsh[((w << 4) + m16) * 72       + 32 + (quad << 3)]);
            half8 q1 = *(const half8*)(&Wsh[(32 + (w << 4) + m16) * 72  + 32 + (quad << 3)]);
            half8 q2 = *(const half8*)(&Wsh[(64 + (w << 4) + m16) * 72  + 32 + (quad << 3)]);
            acc_r  = __builtin_amdgcn_mfma_f32_16x16x32_f16(ax1, q0, acc_r,  0, 0, 0);
            acc_z  = __builtin_amdgcn_mfma_f32_16x16x32_f16(ax1, q1, acc_z,  0, 0, 0);
            acc_in = __builtin_amdgcn_mfma_f32_16x16x32_f16(ax1, q2, acc_in, 0, 0, 0);
        }

        // 4 phases: write staged A -> barrier -> poll+issue next -> MFMA this phase
        #pragma unroll
        for (int g = 0; g < 4; ++g) {
            {
                _Float16* d = &Ash[srow * 1032 + (g << 8) + (sch << 5)];
                #pragma unroll
                for (int j = 0; j < 8; ++j) *(u64*)(d + (j << 2)) = va[j];
            }
            __syncthreads();
            if (g < 3) {
                const u64 mask = 0xFFFFull << ((g + 1) << 4);
                while ((rdy & mask) != mask) {
                    unsigned f = __hip_atomic_load(flag_peer, __ATOMIC_RELAXED, __HIP_MEMORY_SCOPE_AGENT);
                    rdy |= __ballot(f >= need);
                    if ((rdy & mask) != mask) __builtin_amdgcn_s_sleep(1);
                }
                const _Float16* s = hsrc + ((size_t)(pi16 + srow) << 10) + ((g + 1) << 8) + (sch << 5);
                #pragma unroll
                for (int j = 0; j < 8; ++j)
                    va[j] = __hip_atomic_load((const u64*)(s + (j << 2)), __ATOMIC_RELAXED, __HIP_MEMORY_SCOPE_AGENT);
                #pragma unroll
                for (int j = 0; j < 8; ++j)
                    bnB[j] = *(const half8*)(bnp + ((((g + 1) << 3) + j) << 5));
            }
            #pragma unroll
            for (int j = 0; j < 8; ++j) {
                const int c = (g << 3) + j;
                half8 a = *(const half8*)(&Ash[m16 * 1032 + (c << 5) + (quad << 3)]);
                acc_r  = __builtin_amdgcn_mfma_f32_16x16x32_f16(a, br[c], acc_r,  0, 0, 0);
                acc_z  = __builtin_amdgcn_mfma_f32_16x16x32_f16(a, bz[c], acc_z,  0, 0, 0);
                acc_hn = __builtin_amdgcn_mfma_f32_16x16x32_f16(a, bnA[j], acc_hn, 0, 0, 0);
            }
            if (g < 3) {
                #pragma unroll
                for (int j = 0; j < 8; ++j) bnA[j] = bnB[j];
            }
        }

        // epilogue (per-wave; no barrier before publish)
        float pv[4];
        #pragma unroll
        for (int i = 0; i < 4; ++i) {
            float rg = fast_sigmoid(acc_r[i]);
            float zg = fast_sigmoid(acc_z[i]);
            float ng = fast_tanh(acc_in[i] + rg * acc_hn[i]);
            float hn2 = (1.f - zg) * ng + zg * hreg[i];
            hreg[i] = hn2;
            pv[i] = hn2 * wo_u;
            Hsh[(w << 8) + ((quad << 2) + i) * 16 + m16] = (_Float16)hn2;
        }
        __threadfence_block();   // order f16 Hsh writes before u64 read (R9 fix)
        {
            u64 hv = *(const u64*)(&Hsh[(w << 8) + prow * 16 + (pc4 << 2)]);
            __hip_atomic_store(
                (u64*)(hdst + ((size_t)(pi16 + prow) << 10) + (qi << 5) + (w << 4) + (pc4 << 2)),
                hv, __ATOMIC_RELAXED, __HIP_MEMORY_SCOPE_AGENT);
        }
        asm volatile("s_waitcnt vmcnt(0)" ::: "memory");  // this wave's publish drained
        if (lane == 0)
            __hip_atomic_store(flag_self, (unsigned)(t + 1),
                               __ATOMIC_RELAXED, __HIP_MEMORY_SCOPE_AGENT);
        #pragma unroll
        for (int m = 1; m < 16; m <<= 1) {
            #pragma unroll
            for (int i = 0; i < 4; ++i) pv[i] += __shfl_xor(pv[i], m);
        }
        if (m16 == 0) {
            #pragma unroll
            for (int i = 0; i < 4; ++i)
                partials[((size_t)t * B_ + pi16 + (quad << 2) + i) * 64 + (qi << 1) + w] = pv[i];
        }
    }
}

// ---------------- final reduce ----------------
__global__ void out_reduce(const float* __restrict__ partials, const float* __restrict__ bo,
                           float* __restrict__ out) {
    int t = blockIdx.x, r = threadIdx.x;
    const float* p = partials + ((size_t)t * B_ + r) * 64;
    float s = 0.f;
    #pragma unroll
    for (int i = 0; i < 64; ++i) s += p[i];
    out[(size_t)r * T_ + t] = s + bo[0];
}

extern "C" void kernel_launch(void* const* d_in, const int* in_sizes, int n_in,
                              void* d_out, int out_size, void* d_ws, size_t ws_size,
                              hipStream_t stream) {
    const float* lag  = (const float*)d_in[0];
    const float* curr = (const float*)d_in[1];
    const float* W1   = (const float*)d_in[2];
    const float* b1   = (const float*)d_in[3];
    const float* W2   = (const float*)d_in[4];
    const float* b2   = (const float*)d_in[5];
    const float* W3   = (const float*)d_in[6];
    const float* b3   = (const float*)d_in[7];
    const float* Wih  = (const float*)d_in[8];
    const float* Whh  = (const float*)d_in[9];
    const float* bih  = (const float*)d_in[10];
    const float* bhh  = (const float*)d_in[11];
    const float* Wo   = (const float*)d_in[12];
    const float* bo   = (const float*)d_in[13];
    float* out = (float*)d_out;

    char* ws = (char*)d_ws;
    size_t off = 0;
    auto alloc = [&](size_t bytes) -> void* {
        void* p = ws + off;
        off += (bytes + 255) & ~(size_t)255;
        return p;
    };
    _Float16* whh16 = (_Float16*)alloc((size_t)3 * H_ * H_ * 2);
    _Float16* wih16 = (_Float16*)alloc((size_t)3 * H_ * WS_ * 2);
    _Float16* x16   = (_Float16*)alloc((size_t)T_ * B_ * WS_ * 2);
    _Float16* hbuf  = (_Float16*)alloc((size_t)4 * B_ * H_ * 2);
    float* hprev32  = (float*)alloc((size_t)B_ * H_ * 4);
    float* h1       = (float*)alloc((size_t)B_ * 64 * 4);
    float* h2       = (float*)alloc((size_t)B_ * LAT_ * 4);
    float* partials = (float*)alloc((size_t)T_ * B_ * 64 * 4);
    unsigned* bar   = (unsigned*)alloc(81920);

    hipMemsetAsync(bar, 0, 81920, stream);

    int n4;
    n4 = 3 * H_ * H_ / 4;
    cvt_f32_f16_v4<<<(n4 + 255) / 256, 256, 0, stream>>>((const float4*)Whh, (half4*)whh16, n4);
    n4 = 3 * H_ * WS_ / 4;
    cvt_f32_f16_v4<<<(n4 + 255) / 256, 256, 0, stream>>>((const float4*)Wih, (half4*)wih16, n4);
    n4 = T_ * B_ * WS_ / 4;
    cvt_f32_f16_v4<<<(n4 + 255) / 256, 256, 0, stream>>>((const float4*)curr, (half4*)x16, n4);

    enc12<<<B_, 64, 0, stream>>>(lag, W1, b1, h1, LAG_);
    enc12<<<B_, LAT_, 0, stream>>>(h1, W2, b2, h2, 64);
    enc3<<<B_, 256, 0, stream>>>(h2, W3, b3, hprev32, hbuf);

    gru_persistent<<<dim3(512), dim3(128), 0, stream>>>(
        hbuf, hprev32, whh16, wih16, x16, bih, bhh, Wo, partials, bar);

    out_reduce<<<T_, B_, 0, stream>>>(partials, bo, out);
}

// Round 11
// 1033.550 us; speedup vs baseline: 1.3446x; 1.3446x over previous
//
#include <hip/hip_runtime.h>
#include <hip/hip_bf16.h>
#include <cstdint>
#include <cstddef>

typedef _Float16 half8 __attribute__((ext_vector_type(8)));
typedef _Float16 half4 __attribute__((ext_vector_type(4)));
typedef float floatx4 __attribute__((ext_vector_type(4)));
typedef unsigned long long u64;

#define B_ 256
#define T_ 168
#define H_ 1024
#define WS_ 64
#define LAG_ 168
#define LAT_ 128

__device__ __forceinline__ float fast_sigmoid(float x) {
    return __builtin_amdgcn_rcpf(1.f + __expf(-x));
}
__device__ __forceinline__ float fast_tanh(float x) {
    return 1.f - 2.f * __builtin_amdgcn_rcpf(__expf(2.f * x) + 1.f);
}

// ---------------- fp32 -> fp16 conversion ----------------
__global__ void cvt_f32_f16_v4(const float4* __restrict__ src, half4* __restrict__ dst, int n4) {
    int i = blockIdx.x * blockDim.x + threadIdx.x;
    if (i < n4) {
        float4 v = src[i];
        half4 o;
        o[0] = (_Float16)v.x; o[1] = (_Float16)v.y;
        o[2] = (_Float16)v.z; o[3] = (_Float16)v.w;
        dst[i] = o;
    }
}

// ---------------- encoder layers 1,2 ----------------
__global__ void enc12(const float* __restrict__ in, const float* __restrict__ W,
                      const float* __restrict__ bias, float* __restrict__ outb, int infeat) {
    int r = blockIdx.x, j = threadIdx.x;
    const float* row = in + (size_t)r * infeat;
    const float* w   = W  + (size_t)j * infeat;
    float s = bias[j];
    for (int k = 0; k < infeat; ++k) s += row[k] * w[k];
    outb[(size_t)r * blockDim.x + j] = (s >= 0.f) ? s : 0.01f * s;
}

// ---------------- encoder layer 3 ----------------
__global__ void enc3(const float* __restrict__ h2, const float* __restrict__ W3,
                     const float* __restrict__ b3, float* __restrict__ hprev32,
                     _Float16* __restrict__ h0f16) {
    __shared__ float s[LAT_];
    int r = blockIdx.x;
    if (threadIdx.x < LAT_) s[threadIdx.x] = h2[(size_t)r * LAT_ + threadIdx.x];
    __syncthreads();
    for (int j = threadIdx.x; j < H_; j += 256) {
        const float* w = W3 + (size_t)j * LAT_;
        float acc = b3[j];
        #pragma unroll 8
        for (int k = 0; k < LAT_; ++k) acc += s[k] * w[k];
        hprev32[(size_t)r * H_ + j] = acc;
        h0f16[(size_t)r * H_ + j]   = (_Float16)acc;
    }
}

// ---------------- persistent GRU: speculative staging + post-validation ----------------
// R9 shape (best known: 256 WGs x 256 thr, pi=blk&15, qi=blk>>4, rz Whh resident
// in AGPRs, n streamed 8+8, per-wave flags, 4-phase K-loop, threadfence before
// u64 publish read). R11 delta: NO blocking polls. All phase loads issued
// speculatively; staging thread's 32B chunk == slice (16g+sch); chunk valid iff
// its flag bit was confirmed BEFORE issue (rdy mask gathered during previous
// epilogue); unconfirmed chunks spin on own flag + reload just before Ash write.
// Ring depth 4 still safe: producer lead <= slot (t+2)&3 vs consumer slot t&3.
__global__ __launch_bounds__(256, 1) void gru_persistent(
    _Float16* __restrict__ hbuf,
    const float* __restrict__ hprev32, const _Float16* __restrict__ whh16,
    const _Float16* __restrict__ wih16, const _Float16* __restrict__ x16,
    const float* __restrict__ bih, const float* __restrict__ bhh,
    const float* __restrict__ Wo, float* __restrict__ partials,
    unsigned* __restrict__ bar)
{
    __shared__ __align__(16) _Float16 Ash[16 * 1032];
    __shared__ __align__(16) _Float16 Wsh[192 * 72];
    __shared__ __align__(16) _Float16 Hsh[4 * 256];

    const int tid  = threadIdx.x;
    const int w    = tid >> 6;
    const int lane = tid & 63;
    const int m16  = lane & 15;
    const int quad = lane >> 4;
    const int pi   = blockIdx.x & 15;
    const int qi   = blockIdx.x >> 4;
    const int pi16 = pi << 4;
    const int u    = (qi << 6) + (w << 4) + m16;

    // Wih slice -> LDS (once)
    for (int idx = tid; idx < 1536; idx += 256) {
        int rowl = idx >> 3, ch = idx & 7;
        int g = rowl >> 6, ru = rowl & 63;
        *(uint4*)(&Wsh[rowl * 72 + (ch << 3)]) =
            *(const uint4*)(wih16 + (size_t)(((g << 10) + (qi << 6) + ru) << 6) + (ch << 3));
    }

    // Resident Whh: r,z gates (AGPR-backed)
    half8 br[32], bz[32];
    {
        const _Float16* p0 = whh16 + ((size_t)u << 10) + (quad << 3);
        const _Float16* p1 = whh16 + ((size_t)(H_ + u) << 10) + (quad << 3);
        #pragma unroll
        for (int c = 0; c < 32; ++c) br[c] = *(const half8*)(p0 + (c << 5));
        #pragma unroll
        for (int c = 0; c < 32; ++c) bz[c] = *(const half8*)(p1 + (c << 5));
    }
    const _Float16* bnp = whh16 + ((size_t)(2 * H_ + u) << 10) + (quad << 3);

    const float b_r  = bih[u]          + bhh[u];
    const float b_z  = bih[H_ + u]     + bhh[H_ + u];
    const float b_in = bih[2 * H_ + u];
    const float b_hn = bhh[2 * H_ + u];
    const float wo_u = Wo[u];

    float hreg[4];
    #pragma unroll
    for (int i = 0; i < 4; ++i)
        hreg[i] = hprev32[((size_t)(pi16 + (quad << 2) + i) << 10) + u];

    __syncthreads();

    // flags: index (pi<<6 | slice), 64B lines; slice s covers units 64*(s>>2)+16*(s&3)
    unsigned* flag_self       = bar + ((((pi << 4) | qi) << 2 | w) << 4);
    const unsigned* flag_peer = bar + (((pi << 6) | lane) << 4);
    const int srow = tid >> 4;     // staging row 0..15
    const int sch  = tid & 15;     // 32B chunk == slice (16g+sch) within phase g
    const int prow = lane >> 2;    // publish row, 8B chunk
    const int pc4  = lane & 3;

    u64 rdy = 0;   // bit l: flag[pi][l] confirmed >= current t (pre-issue confirmation)

    for (int t = 0; t < T_; ++t) {
        const _Float16* hsrc = hbuf + (size_t)(t & 3) * (B_ * H_);
        _Float16*       hdst = hbuf + (size_t)((t + 1) & 3) * (B_ * H_);
        const unsigned need = (unsigned)t;

        // speculative phase-0 A loads (issued FIRST so later ax-waits drain them too)
        u64 va0, va1, va2, va3;
        {
            const _Float16* s = hsrc + ((size_t)(pi16 + srow) << 10) + (sch << 4);
            va0 = __hip_atomic_load((const u64*)(s + 0),  __ATOMIC_RELAXED, __HIP_MEMORY_SCOPE_AGENT);
            va1 = __hip_atomic_load((const u64*)(s + 4),  __ATOMIC_RELAXED, __HIP_MEMORY_SCOPE_AGENT);
            va2 = __hip_atomic_load((const u64*)(s + 8),  __ATOMIC_RELAXED, __HIP_MEMORY_SCOPE_AGENT);
            va3 = __hip_atomic_load((const u64*)(s + 12), __ATOMIC_RELAXED, __HIP_MEMORY_SCOPE_AGENT);
        }
        // h-independent prefetch
        half8 ax0 = *(const half8*)(x16 + (((size_t)t << 8) + pi16 + m16) * WS_ + (quad << 3));
        half8 ax1 = *(const half8*)(x16 + (((size_t)t << 8) + pi16 + m16) * WS_ + 32 + (quad << 3));
        half8 bnA[8], bnB[8];
        #pragma unroll
        for (int j = 0; j < 8; ++j) bnA[j] = *(const half8*)(bnp + (j << 5));

        floatx4 acc_r  = {b_r,  b_r,  b_r,  b_r };
        floatx4 acc_z  = {b_z,  b_z,  b_z,  b_z };
        floatx4 acc_in = {b_in, b_in, b_in, b_in};
        floatx4 acc_hn = {b_hn, b_hn, b_hn, b_hn};

        // gi = x_t @ Wih^T — h-independent, covers the phase-0 validation window
        {
            half8 p0 = *(const half8*)(&Wsh[((w << 4) + m16) * 72        + (quad << 3)]);
            half8 p1 = *(const half8*)(&Wsh[(64 + (w << 4) + m16) * 72   + (quad << 3)]);
            half8 p2 = *(const half8*)(&Wsh[(128 + (w << 4) + m16) * 72  + (quad << 3)]);
            acc_r  = __builtin_amdgcn_mfma_f32_16x16x32_f16(ax0, p0, acc_r,  0, 0, 0);
            acc_z  = __builtin_amdgcn_mfma_f32_16x16x32_f16(ax0, p1, acc_z,  0, 0, 0);
            acc_in = __builtin_amdgcn_mfma_f32_16x16x32_f16(ax0, p2, acc_in, 0, 0, 0);
            half8 q0 = *(const half8*)(&Wsh[((w << 4) + m16) * 72        + 32 + (quad << 3)]);
            half8 q1 = *(const half8*)(&Wsh[(64 + (w << 4) + m16) * 72   + 32 + (quad << 3)]);
            half8 q2 = *(const half8*)(&Wsh[(128 + (w << 4) + m16) * 72  + 32 + (quad << 3)]);
            acc_r  = __builtin_amdgcn_mfma_f32_16x16x32_f16(ax1, q0, acc_r,  0, 0, 0);
            acc_z  = __builtin_amdgcn_mfma_f32_16x16x32_f16(ax1, q1, acc_z,  0, 0, 0);
            acc_in = __builtin_amdgcn_mfma_f32_16x16x32_f16(ax1, q2, acc_in, 0, 0, 0);
        }

        // 4 phases: validate spec va -> write Ash -> barrier -> spec-issue next -> MFMA
        #pragma unroll
        for (int g = 0; g < 4; ++g) {
            // validation: chunk valid iff flag bit (16g+sch) confirmed before issue
            {
                const int myslice = (g << 4) + sch;
                if (!((rdy >> myslice) & 1)) {
                    const unsigned* fp = bar + (((pi << 6) | myslice) << 4);
                    unsigned f = __hip_atomic_load(fp, __ATOMIC_RELAXED, __HIP_MEMORY_SCOPE_AGENT);
                    while (f < need) {
                        __builtin_amdgcn_s_sleep(1);
                        f = __hip_atomic_load(fp, __ATOMIC_RELAXED, __HIP_MEMORY_SCOPE_AGENT);
                    }
                    // flag confirmed AFTER spec issue -> reload (now ordered-fresh)
                    const _Float16* s = hsrc + ((size_t)(pi16 + srow) << 10) + (g << 8) + (sch << 4);
                    va0 = __hip_atomic_load((const u64*)(s + 0),  __ATOMIC_RELAXED, __HIP_MEMORY_SCOPE_AGENT);
                    va1 = __hip_atomic_load((const u64*)(s + 4),  __ATOMIC_RELAXED, __HIP_MEMORY_SCOPE_AGENT);
                    va2 = __hip_atomic_load((const u64*)(s + 8),  __ATOMIC_RELAXED, __HIP_MEMORY_SCOPE_AGENT);
                    va3 = __hip_atomic_load((const u64*)(s + 12), __ATOMIC_RELAXED, __HIP_MEMORY_SCOPE_AGENT);
                }
            }
            {
                _Float16* d = &Ash[srow * 1032 + (g << 8) + (sch << 4)];
                *(u64*)(d + 0)  = va0;
                *(u64*)(d + 4)  = va1;
                *(u64*)(d + 8)  = va2;
                *(u64*)(d + 12) = va3;
            }
            __syncthreads();
            if (g < 3) {
                // speculative issue of phase g+1 (no readiness requirement)
                const _Float16* s = hsrc + ((size_t)(pi16 + srow) << 10) + ((g + 1) << 8) + (sch << 4);
                va0 = __hip_atomic_load((const u64*)(s + 0),  __ATOMIC_RELAXED, __HIP_MEMORY_SCOPE_AGENT);
                va1 = __hip_atomic_load((const u64*)(s + 4),  __ATOMIC_RELAXED, __HIP_MEMORY_SCOPE_AGENT);
                va2 = __hip_atomic_load((const u64*)(s + 8),  __ATOMIC_RELAXED, __HIP_MEMORY_SCOPE_AGENT);
                va3 = __hip_atomic_load((const u64*)(s + 12), __ATOMIC_RELAXED, __HIP_MEMORY_SCOPE_AGENT);
                #pragma unroll
                for (int j = 0; j < 8; ++j)
                    bnB[j] = *(const half8*)(bnp + ((((g + 1) << 3) + j) << 5));
            }
            #pragma unroll
            for (int j = 0; j < 8; ++j) {
                const int c = (g << 3) + j;
                half8 a = *(const half8*)(&Ash[m16 * 1032 + (c << 5) + (quad << 3)]);
                acc_r  = __builtin_amdgcn_mfma_f32_16x16x32_f16(a, br[c], acc_r,  0, 0, 0);
                acc_z  = __builtin_amdgcn_mfma_f32_16x16x32_f16(a, bz[c], acc_z,  0, 0, 0);
                acc_hn = __builtin_amdgcn_mfma_f32_16x16x32_f16(a, bnA[j], acc_hn, 0, 0, 0);
            }
            if (g < 3) {
                #pragma unroll
                for (int j = 0; j < 8; ++j) bnA[j] = bnB[j];
            }
        }

        // epilogue (per-wave; no barrier before publish)
        float pv[4];
        #pragma unroll
        for (int i = 0; i < 4; ++i) {
            float rg = fast_sigmoid(acc_r[i]);
            float zg = fast_sigmoid(acc_z[i]);
            float ng = fast_tanh(acc_in[i] + rg * acc_hn[i]);
            float hn2 = (1.f - zg) * ng + zg * hreg[i];
            hreg[i] = hn2;
            pv[i] = hn2 * wo_u;
            Hsh[(w << 8) + ((quad << 2) + i) * 16 + m16] = (_Float16)hn2;
        }
        __threadfence_block();   // order f16 Hsh writes before u64 read (R9 fix)
        {
            u64 hv = *(const u64*)(&Hsh[(w << 8) + prow * 16 + (pc4 << 2)]);
            __hip_atomic_store(
                (u64*)(hdst + ((size_t)(pi16 + prow) << 10) + (qi << 6) + (w << 4) + (pc4 << 2)),
                hv, __ATOMIC_RELAXED, __HIP_MEMORY_SCOPE_AGENT);
        }
        asm volatile("s_waitcnt vmcnt(0)" ::: "memory");  // publish drained
        if (lane == 0)
            __hip_atomic_store(flag_self, (unsigned)(t + 1),
                               __ATOMIC_RELAXED, __HIP_MEMORY_SCOPE_AGENT);

        // opportunistic readiness gather for next step (overlaps peers' publishing;
        // pv-reduce and partials store hide the flag RT)
        u64 rdy_next = 0;
        unsigned f1 = 0;
        if (t < T_ - 1)
            f1 = __hip_atomic_load(flag_peer, __ATOMIC_RELAXED, __HIP_MEMORY_SCOPE_AGENT);
        #pragma unroll
        for (int m = 1; m < 16; m <<= 1) {
            #pragma unroll
            for (int i = 0; i < 4; ++i) pv[i] += __shfl_xor(pv[i], m);
        }
        if (t < T_ - 1)
            rdy_next = __ballot(f1 >= (unsigned)(t + 1));
        if (m16 == 0) {
            #pragma unroll
            for (int i = 0; i < 4; ++i)
                partials[((size_t)t * B_ + pi16 + (quad << 2) + i) * 64 + (qi << 2) + w] = pv[i];
        }
        if (t < T_ - 1 && rdy_next != ~0ull) {
            unsigned f2 = __hip_atomic_load(flag_peer, __ATOMIC_RELAXED, __HIP_MEMORY_SCOPE_AGENT);
            rdy_next |= __ballot(f2 >= (unsigned)(t + 1));
        }
        rdy = rdy_next;
    }
}

// ---------------- final reduce ----------------
__global__ void out_reduce(const float* __restrict__ partials, const float* __restrict__ bo,
                           float* __restrict__ out) {
    int t = blockIdx.x, r = threadIdx.x;
    const float* p = partials + ((size_t)t * B_ + r) * 64;
    float s = 0.f;
    #pragma unroll
    for (int i = 0; i < 64; ++i) s += p[i];
    out[(size_t)r * T_ + t] = s + bo[0];
}

extern "C" void kernel_launch(void* const* d_in, const int* in_sizes, int n_in,
                              void* d_out, int out_size, void* d_ws, size_t ws_size,
                              hipStream_t stream) {
    const float* lag  = (const float*)d_in[0];
    const float* curr = (const float*)d_in[1];
    const float* W1   = (const float*)d_in[2];
    const float* b1   = (const float*)d_in[3];
    const float* W2   = (const float*)d_in[4];
    const float* b2   = (const float*)d_in[5];
    const float* W3   = (const float*)d_in[6];
    const float* b3   = (const float*)d_in[7];
    const float* Wih  = (const float*)d_in[8];
    const float* Whh  = (const float*)d_in[9];
    const float* bih  = (const float*)d_in[10];
    const float* bhh  = (const float*)d_in[11];
    const float* Wo   = (const float*)d_in[12];
    const float* bo   = (const float*)d_in[13];
    float* out = (float*)d_out;

    char* ws = (char*)d_ws;
    size_t off = 0;
    auto alloc = [&](size_t bytes) -> void* {
        void* p = ws + off;
        off += (bytes + 255) & ~(size_t)255;
        return p;
    };
    _Float16* whh16 = (_Float16*)alloc((size_t)3 * H_ * H_ * 2);
    _Float16* wih16 = (_Float16*)alloc((size_t)3 * H_ * WS_ * 2);
    _Float16* x16   = (_Float16*)alloc((size_t)T_ * B_ * WS_ * 2);
    _Float16* hbuf  = (_Float16*)alloc((size_t)4 * B_ * H_ * 2);
    float* hprev32  = (float*)alloc((size_t)B_ * H_ * 4);
    float* h1       = (float*)alloc((size_t)B_ * 64 * 4);
    float* h2       = (float*)alloc((size_t)B_ * LAT_ * 4);
    float* partials = (float*)alloc((size_t)T_ * B_ * 64 * 4);
    unsigned* bar   = (unsigned*)alloc(81920);

    hipMemsetAsync(bar, 0, 81920, stream);

    int n4;
    n4 = 3 * H_ * H_ / 4;
    cvt_f32_f16_v4<<<(n4 + 255) / 256, 256, 0, stream>>>((const float4*)Whh, (half4*)whh16, n4);
    n4 = 3 * H_ * WS_ / 4;
    cvt_f32_f16_v4<<<(n4 + 255) / 256, 256, 0, stream>>>((const float4*)Wih, (half4*)wih16, n4);
    n4 = T_ * B_ * WS_ / 4;
    cvt_f32_f16_v4<<<(n4 + 255) / 256, 256, 0, stream>>>((const float4*)curr, (half4*)x16, n4);

    enc12<<<B_, 64, 0, stream>>>(lag, W1, b1, h1, LAG_);
    enc12<<<B_, LAT_, 0, stream>>>(h1, W2, b2, h2, 64);
    enc3<<<B_, 256, 0, stream>>>(h2, W3, b3, hprev32, hbuf);

    gru_persistent<<<dim3(256), dim3(256), 0, stream>>>(
        hbuf, hprev32, whh16, wih16, x16, bih, bhh, Wo, partials, bar);

    out_reduce<<<T_, B_, 0, stream>>>(partials, bo, out);
}